// Round 1
// baseline (881.935 us; speedup 1.0000x reference)
//
#include <hip/hip_runtime.h>
#include <hip/hip_bf16.h>

// ---------------------------------------------------------------------------
// TGSA: x = img[:,1:]; S = XX^T/sqrt(D); A=softmax(S); msg=AX;
//       x += g_gcn * (W2 gelu(W1 msg + b1) + b2);
//       tq = LN(W2t gelu(W1t text + b1t) + b2t);
//       out[:,1:] = x * (1 + g * sigmoid(x . tq)); out[:,0] = cls
//
// Strategy: all 4 big GEMMs via one bf16-MFMA 128x128 "bt" kernel
// (m97 structure: global_load_lds width16 staging, 16x16x32 MFMA).
// Token dim padded 196 -> 256 (zeros). w1/w2 pre-transposed; x also stored
// transposed so every GEMM is C[m][n] = sum_k A[m][k] * Bt[n][k].
// ---------------------------------------------------------------------------

#define BATCH 256
#define NTOK  196
#define PN    256          // padded token count (multiple of 128)
#define DIMG  768
#define DTXT  512
#define MROWS (BATCH*NTOK) // 50176 = 392*128
#define LN_EPS 1e-5f

typedef __hip_bfloat16 bf16_t;
typedef __bf16 bf16x8 __attribute__((ext_vector_type(8)));
typedef float  f32x4  __attribute__((ext_vector_type(4)));

typedef const __attribute__((address_space(1))) void gvoid_t;
typedef __attribute__((address_space(3))) void lvoid_t;

__device__ __forceinline__ float gelu_f(float x){
    return 0.5f * x * (1.0f + erff(x * 0.70710678118654752440f));
}

// --- prep: cast x to bf16 (padded) + build x^T (padded) -------------------
__global__ void prep_x(const float* __restrict__ img, bf16_t* __restrict__ xb,
                       bf16_t* __restrict__ xt){
    __shared__ float tile[32][33];
    const int b  = blockIdx.z;
    const int m0 = blockIdx.y * 32;   // 8 tiles over PN
    const int d0 = blockIdx.x * 32;   // 24 tiles over DIMG
    const int tx = threadIdx.x, ty = threadIdx.y;
    #pragma unroll
    for (int i = 0; i < 4; i++){
        const int m = m0 + ty + i*8;
        float v = 0.f;
        if (m < NTOK) v = img[((size_t)b*197 + 1 + m)*DIMG + d0 + tx];
        tile[ty + i*8][tx] = v;
        xb[((size_t)b*PN + m)*DIMG + d0 + tx] = __float2bfloat16(v);
    }
    __syncthreads();
    #pragma unroll
    for (int i = 0; i < 4; i++){
        const int d = d0 + ty + i*8;
        xt[((size_t)b*DIMG + d)*PN + m0 + tx] = __float2bfloat16(tile[tx][ty + i*8]);
    }
}

// --- prep: transpose+cast 768x768 weight --------------------------------
__global__ void prep_w(const float* __restrict__ w, bf16_t* __restrict__ wt){
    __shared__ float tile[32][33];
    const int r0 = blockIdx.y * 32, c0 = blockIdx.x * 32;
    const int tx = threadIdx.x, ty = threadIdx.y;
    #pragma unroll
    for (int i = 0; i < 4; i++)
        tile[ty + i*8][tx] = w[(size_t)(r0 + ty + i*8)*DIMG + c0 + tx];
    __syncthreads();
    #pragma unroll
    for (int i = 0; i < 4; i++)
        wt[(size_t)(c0 + ty + i*8)*DIMG + r0 + tx] = __float2bfloat16(tile[tx][ty + i*8]);
}

// --- cls passthrough ------------------------------------------------------
__global__ void cls_copy(const float* __restrict__ img, float* __restrict__ out){
    const int i = blockIdx.x * 256 + threadIdx.x;   // 256*768 elems exactly
    const int b = i / DIMG, d = i - b*DIMG;
    out[((size_t)b*197)*DIMG + d] = img[((size_t)b*197)*DIMG + d];
}

// --- text branch ----------------------------------------------------------
__global__ void txt_fc1(const float* __restrict__ text, const float* __restrict__ w,
                        const float* __restrict__ bias, float* __restrict__ h){
    __shared__ float ts[DTXT];
    const int b = blockIdx.y;
    const int n = blockIdx.x * 256 + threadIdx.x;
    for (int k = threadIdx.x; k < DTXT; k += 256) ts[k] = text[(size_t)b*DTXT + k];
    __syncthreads();
    float acc = 0.f;
    for (int k = 0; k < DTXT; k++) acc = fmaf(ts[k], w[(size_t)k*DIMG + n], acc);
    h[(size_t)b*DIMG + n] = gelu_f(acc + bias[n]);
}

__global__ void txt_fc2(const float* __restrict__ h, const float* __restrict__ w,
                        const float* __restrict__ bias, float* __restrict__ tq){
    __shared__ float ts[DIMG];
    const int b = blockIdx.y;
    const int n = blockIdx.x * 256 + threadIdx.x;
    for (int k = threadIdx.x; k < DIMG; k += 256) ts[k] = h[(size_t)b*DIMG + k];
    __syncthreads();
    float acc = 0.f;
    for (int k = 0; k < DIMG; k++) acc = fmaf(ts[k], w[(size_t)k*DIMG + n], acc);
    tq[(size_t)b*DIMG + n] = acc + bias[n];
}

__global__ void txt_ln(float* __restrict__ tq, const float* __restrict__ lw,
                       const float* __restrict__ lb){
    __shared__ float red[4];
    const int b = blockIdx.x, t = threadIdx.x;
    const int wv = t >> 6, lane = t & 63;
    float x[3];
    #pragma unroll
    for (int i = 0; i < 3; i++) x[i] = tq[(size_t)b*DIMG + t + i*256];
    float s = x[0] + x[1] + x[2];
    #pragma unroll
    for (int o = 1; o < 64; o <<= 1) s += __shfl_xor(s, o);
    if (lane == 0) red[wv] = s;
    __syncthreads();
    const float mu = (red[0]+red[1]+red[2]+red[3]) * (1.f/768.f);
    float q = 0.f;
    #pragma unroll
    for (int i = 0; i < 3; i++){ const float d = x[i]-mu; q = fmaf(d, d, q); }
    #pragma unroll
    for (int o = 1; o < 64; o <<= 1) q += __shfl_xor(q, o);
    __syncthreads();
    if (lane == 0) red[wv] = q;
    __syncthreads();
    const float var = (red[0]+red[1]+red[2]+red[3]) * (1.f/768.f);
    const float inv = rsqrtf(var + LN_EPS);
    #pragma unroll
    for (int i = 0; i < 3; i++){
        const int d = t + i*256;
        tq[(size_t)b*DIMG + d] = (x[i]-mu)*inv*lw[d] + lb[d];
    }
}

// --- softmax over rows of S (scale 1/sqrt(D), mask padded cols) ----------
__global__ void softmax_k(const float* __restrict__ S, bf16_t* __restrict__ A){
    const int gr = blockIdx.x * 4 + (threadIdx.x >> 6);
    const int lane = threadIdx.x & 63;
    if (gr >= MROWS) return;
    const int b = gr / NTOK, m = gr - b*NTOK;
    const float* row = S + ((size_t)b*PN + m)*PN;
    const float scale = 0.03608439182435161256f;   // 1/sqrt(768)
    float v[4]; float mx = -1e30f;
    #pragma unroll
    for (int i = 0; i < 4; i++){
        const int n = lane + i*64;
        const float val = (n < NTOK) ? row[n]*scale : -1e30f;
        v[i] = val; mx = fmaxf(mx, val);
    }
    #pragma unroll
    for (int o = 1; o < 64; o <<= 1) mx = fmaxf(mx, __shfl_xor(mx, o));
    float sum = 0.f;
    #pragma unroll
    for (int i = 0; i < 4; i++){ v[i] = expf(v[i] - mx); sum += v[i]; }
    #pragma unroll
    for (int o = 1; o < 64; o <<= 1) sum += __shfl_xor(sum, o);
    const float inv = 1.f / sum;
    bf16_t* orow = A + ((size_t)b*PN + m)*PN;
    #pragma unroll
    for (int i = 0; i < 4; i++) orow[lane + i*64] = __float2bfloat16(v[i]*inv);
}

// --- final: out_row *= 1 + gamma*sigmoid(out_row . tq_b) (in place) ------
__global__ void mask_k(float* __restrict__ out, const float* __restrict__ tq,
                       const float* __restrict__ gam){
    const int gr = blockIdx.x * 4 + (threadIdx.x >> 6);
    const int lane = threadIdx.x & 63;
    if (gr >= MROWS) return;
    const int b = gr / NTOK, n = gr - b*NTOK;
    float* row = out + ((size_t)b*197 + 1 + n)*DIMG;
    const float* t = tq + (size_t)b*DIMG;
    float x[12]; float dot = 0.f;
    #pragma unroll
    for (int i = 0; i < 12; i++){
        x[i] = row[lane + i*64];
        dot = fmaf(x[i], t[lane + i*64], dot);
    }
    #pragma unroll
    for (int o = 1; o < 64; o <<= 1) dot += __shfl_xor(dot, o);
    const float sgm = 1.f / (1.f + expf(-dot));
    const float sc = 1.f + gam[0]*sgm;
    #pragma unroll
    for (int i = 0; i < 12; i++) row[lane + i*64] = x[i]*sc;
}

// --- the MFMA GEMM: C[m][n] = sum_k A[m][k]*Bt[n][k], 128x128 tile -------
// MODE 0: G1  -> fp32 S                     (batched, strides in elems)
// MODE 1: G2  -> bf16 msg, row guard <196, row remap to dense [b*196+m]
// MODE 2: G3  -> bf16 h = gelu(C + bias)
// MODE 3: G4  -> fp32 out = res + g*(C + bias), rows remapped to (b,1+n)
template<int MODE>
__global__ __launch_bounds__(256) void gemm_bt(
    const bf16_t* __restrict__ Aall, const bf16_t* __restrict__ Btall,
    int lda, int ldb, int K,
    long long strideA, long long strideB,
    float* __restrict__ outF, bf16_t* __restrict__ outB,
    const float* __restrict__ bias, const float* __restrict__ res,
    const float* __restrict__ gscal)
{
    __shared__ __align__(16) bf16_t sA[128*32];
    __shared__ __align__(16) bf16_t sB[128*32];
    const int b  = blockIdx.z;
    const int m0 = blockIdx.y * 128;
    const int n0 = blockIdx.x * 128;
    const bf16_t* Ab = Aall + (long long)b * strideA;
    const bf16_t* Bb = Btall + (long long)b * strideB;

    const int t    = threadIdx.x;
    const int lane = t & 63;
    const int wave = t >> 6;
    const int wm   = (wave & 1) * 64;
    const int wn   = (wave >> 1) * 64;
    const int fr   = lane & 15;
    const int quad = lane >> 4;

    f32x4 acc[4][4];
    #pragma unroll
    for (int i = 0; i < 4; i++)
        #pragma unroll
        for (int j = 0; j < 4; j++)
            acc[i][j] = (f32x4){0.f, 0.f, 0.f, 0.f};

    const int lin0 = t, lin1 = t + 256;
    const int r0 = lin0 >> 2, s0 = (lin0 & 3) * 8;
    const int r1 = lin1 >> 2, s1 = (lin1 & 3) * 8;

    for (int k0 = 0; k0 < K; k0 += 32){
        __syncthreads();
        __builtin_amdgcn_global_load_lds((gvoid_t*)(Ab + (long long)(m0+r0)*lda + k0 + s0),
                                         (lvoid_t*)(sA + lin0*8), 16, 0, 0);
        __builtin_amdgcn_global_load_lds((gvoid_t*)(Ab + (long long)(m0+r1)*lda + k0 + s1),
                                         (lvoid_t*)(sA + lin1*8), 16, 0, 0);
        __builtin_amdgcn_global_load_lds((gvoid_t*)(Bb + (long long)(n0+r0)*ldb + k0 + s0),
                                         (lvoid_t*)(sB + lin0*8), 16, 0, 0);
        __builtin_amdgcn_global_load_lds((gvoid_t*)(Bb + (long long)(n0+r1)*ldb + k0 + s1),
                                         (lvoid_t*)(sB + lin1*8), 16, 0, 0);
        __syncthreads();
        bf16x8 fa[4], fb[4];
        #pragma unroll
        for (int i = 0; i < 4; i++){
            fa[i] = *(const bf16x8*)(sA + (wm + i*16 + fr)*32 + quad*8);
            fb[i] = *(const bf16x8*)(sB + (wn + i*16 + fr)*32 + quad*8);
        }
        #pragma unroll
        for (int i = 0; i < 4; i++)
            #pragma unroll
            for (int j = 0; j < 4; j++)
                acc[i][j] = __builtin_amdgcn_mfma_f32_16x16x32_bf16(fa[i], fb[j], acc[i][j], 0, 0, 0);
    }

    const float g = (MODE == 3) ? gscal[0] : 0.f;
    #pragma unroll
    for (int i = 0; i < 4; i++){
        #pragma unroll
        for (int j = 0; j < 4; j++){
            #pragma unroll
            for (int r = 0; r < 4; r++){
                const int row = m0 + wm + i*16 + quad*4 + r;   // C/D: row=(lane>>4)*4+reg
                const int col = n0 + wn + j*16 + fr;           //      col=lane&15
                const float v = acc[i][j][r];
                if (MODE == 0){
                    outF[((long long)b*PN + row)*PN + col] = v;
                } else if (MODE == 1){
                    if (row < NTOK)
                        outB[((long long)b*NTOK + row)*DIMG + col] = __float2bfloat16(v);
                } else if (MODE == 2){
                    outB[(long long)row*DIMG + col] = __float2bfloat16(gelu_f(v + bias[col]));
                } else {
                    const int bb = row / NTOK;
                    const int nn = row - bb*NTOK;
                    const long long off = ((long long)bb*197 + 1 + nn)*DIMG + col;
                    outF[off] = res[off] + g*(v + bias[col]);
                }
            }
        }
    }
}

extern "C" void kernel_launch(void* const* d_in, const int* in_sizes, int n_in,
                              void* d_out, int out_size, void* d_ws, size_t ws_size,
                              hipStream_t stream){
    (void)in_sizes; (void)n_in; (void)out_size;
    const float* img  = (const float*)d_in[0];
    const float* text = (const float*)d_in[1];
    const float* w1m  = (const float*)d_in[2];
    const float* b1m  = (const float*)d_in[3];
    const float* w2m  = (const float*)d_in[4];
    const float* b2m  = (const float*)d_in[5];
    const float* ggcn = (const float*)d_in[6];
    const float* w1t  = (const float*)d_in[7];
    const float* b1t  = (const float*)d_in[8];
    const float* w2t  = (const float*)d_in[9];
    const float* b2t  = (const float*)d_in[10];
    const float* lnw  = (const float*)d_in[11];
    const float* lnb  = (const float*)d_in[12];
    const float* gam  = (const float*)d_in[13];
    float* out = (float*)d_out;

    char* p = (char*)d_ws;
    auto alloc = [&](size_t n){ void* r = (void*)p; p += (n + 255) & ~(size_t)255; return r; };
    bf16_t* x_bf   = (bf16_t*)alloc((size_t)BATCH*PN*DIMG*2);
    bf16_t* xT_bf  = (bf16_t*)alloc((size_t)BATCH*DIMG*PN*2);
    float*  S      = (float*) alloc((size_t)BATCH*PN*PN*4);
    bf16_t* A_bf   = (bf16_t*)alloc((size_t)BATCH*PN*PN*2);
    bf16_t* msg_bf = (bf16_t*)alloc((size_t)MROWS*DIMG*2);
    bf16_t* h_bf   = (bf16_t*)alloc((size_t)MROWS*DIMG*2);
    bf16_t* w1T    = (bf16_t*)alloc((size_t)DIMG*DIMG*2);
    bf16_t* w2T    = (bf16_t*)alloc((size_t)DIMG*DIMG*2);
    float*  htxt   = (float*) alloc((size_t)BATCH*DIMG*4);
    float*  tq     = (float*) alloc((size_t)BATCH*DIMG*4);
    if ((size_t)(p - (char*)d_ws) > ws_size) return;  // ws too small: bail (will fail bench visibly)

    prep_x<<<dim3(24, 8, BATCH), dim3(32, 8), 0, stream>>>(img, x_bf, xT_bf);
    prep_w<<<dim3(24, 24), dim3(32, 8), 0, stream>>>(w1m, w1T);
    prep_w<<<dim3(24, 24), dim3(32, 8), 0, stream>>>(w2m, w2T);
    cls_copy<<<dim3(768), dim3(256), 0, stream>>>(img, out);
    txt_fc1<<<dim3(3, BATCH), dim3(256), 0, stream>>>(text, w1t, b1t, htxt);
    txt_fc2<<<dim3(3, BATCH), dim3(256), 0, stream>>>(htxt, w2t, b2t, tq);
    txt_ln<<<dim3(BATCH), dim3(256), 0, stream>>>(tq, lnw, lnb);

    // G1: S = X X^T (batched)
    gemm_bt<0><<<dim3(2, 2, BATCH), dim3(256), 0, stream>>>(
        x_bf, x_bf, DIMG, DIMG, DIMG,
        (long long)PN*DIMG, (long long)PN*DIMG, S, nullptr, nullptr, nullptr, nullptr);
    softmax_k<<<dim3(MROWS/4), dim3(256), 0, stream>>>(S, A_bf);
    // G2: msg = A X  (Bt = X^T)
    gemm_bt<1><<<dim3(6, 2, BATCH), dim3(256), 0, stream>>>(
        A_bf, xT_bf, PN, PN, PN,
        (long long)PN*PN, (long long)DIMG*PN, nullptr, msg_bf, nullptr, nullptr, nullptr);
    // G3: h = gelu(msg @ w1 + b1)
    gemm_bt<2><<<dim3(6, 392, 1), dim3(256), 0, stream>>>(
        msg_bf, w1T, DIMG, DIMG, DIMG,
        0, 0, nullptr, h_bf, b1m, nullptr, nullptr);
    // G4: out rows 1..196 = img + g_gcn*(h @ w2 + b2)
    gemm_bt<3><<<dim3(6, 392, 1), dim3(256), 0, stream>>>(
        h_bf, w2T, DIMG, DIMG, DIMG,
        0, 0, out, nullptr, b2m, img, ggcn);
    mask_k<<<dim3(MROWS/4), dim3(256), 0, stream>>>(out, tq, gam);
}